// Round 2
// baseline (414.844 us; speedup 1.0000x reference)
//
#include <hip/hip_runtime.h>
#include <math.h>

// Problem constants (fixed shapes from setup_inputs)
constexpr int TOPK = 8;
constexpr int NUM_SPECIAL = 999;
constexpr int V = 30522;
constexpr int D = 768;
constexpr int BLOCK = 256;
// Row base is only 8B-aligned when pos is odd (V%4==2). We peel 2 floats
// (tail for even pos, head for odd pos) so the float4 body is 16B-aligned.
constexpr int V4 = 7630;                       // aligned float4 count per row
constexpr int NK4 = (V4 + BLOCK - 1) / BLOCK;  // 30 float4 per thread stream
constexpr int CAP = 512;                       // candidate buffer (ties safety)
constexpr int HOTCAP = 64;                     // hot-thread list bound

// Monotone map float -> uint32 (order-preserving), packed with ~idx so that
// larger key == (larger value, then SMALLER index) -- matches jax.lax.top_k
// tie-breaking (lower index first among equal values).
__device__ __forceinline__ unsigned long long fkey(float v, unsigned int idx) {
    unsigned int u = __float_as_uint(v);
    u = ((int)u < 0) ? ~u : (u | 0x80000000u);
    return ((unsigned long long)u << 32) | (unsigned long long)(~idx);
}

__device__ __forceinline__ float hmax4(float4 f) {
    return fmaxf(fmaxf(f.x, f.y), fmaxf(f.z, f.w));
}

// branchless sorted-desc top-8 insert (2 VALU per stage: v_max/v_min)
__device__ __forceinline__ void net8(float (&L)[TOPK], float t) {
    #pragma unroll
    for (int j = 0; j < TOPK; ++j) {
        float m = fmaxf(L[j], t); t = fminf(L[j], t); L[j] = m;
    }
}

// Per-wave exact top-8 extraction from 64 sorted-desc 8-lists (pops heads).
// Deterministic tie-break by lane id. lane 0 writes the 8 values to dst[0..8).
__device__ __forceinline__ void wave_extract8(float (&cur)[TOPK], int lane,
                                              float* dst) {
    #pragma unroll
    for (int r = 0; r < TOPK; ++r) {
        float m = cur[0];
        int ml = lane;
        #pragma unroll
        for (int off = 1; off < 64; off <<= 1) {
            float om = __shfl_xor(m, off, 64);
            int   ol = __shfl_xor(ml, off, 64);
            if (om > m || (om == m && ol < ml)) { m = om; ml = ol; }
        }
        if (lane == ml) {                      // winner pops its head
            #pragma unroll
            for (int j = 0; j < TOPK - 1; ++j) cur[j] = cur[j + 1];
            cur[TOPK - 1] = -INFINITY;
        }
        if (lane == 0) dst[r] = m;
    }
}

// ======================= Kernel 1: top-8 token ids =========================
// Pure streaming + threshold + sparse rescan + wave-0 selection.
// Writes the 8 top-k candidate token ids (value desc, index asc -- exact
// jax.lax.top_k order) for each position into cand_out[pos*8 + k].
__global__ __launch_bounds__(BLOCK, 8) void dvat_topk(
    const float* __restrict__ pred_lm,      // [B,S,V]
    int* __restrict__ cand_out)             // [B*S, 8]
{
    const int pos = blockIdx.x;
    const int tid = threadIdx.x;
    const int lane = tid & 63;
    const int wave = tid >> 6;

    __shared__ float  smax[BLOCK];                // per-thread stream maxes
    __shared__ float  sm8[TOPK];
    __shared__ float  s_g8;
    __shared__ int    s_hot[HOTCAP];
    __shared__ int    s_nhot;
    __shared__ int    s_ncand;
    __shared__ unsigned long long sh_cand64[CAP]; // 4 KB

    if (tid == 0) { s_nhot = 0; s_ncand = 0; }

    const float* rowf = pred_lm + (size_t)pos * V;
    const int ofs = (pos & 1) << 1;               // 0 (even pos) or 2 (odd pos)
    const float4* row4 = (const float4*)(rowf + ofs);   // 16B-aligned body

    // ---------------- Pass 1: per-thread stream MAX, MLP = 8 ----------------
    float m[8];
    #pragma unroll
    for (int j = 0; j < 8; ++j) m[j] = -INFINITY;

    int i = tid;
    for (int q = 0; q < 3; ++q, i += 8 * BLOCK) { // 24*256 = 6144 float4
        float4 f0 = row4[i];
        float4 f1 = row4[i + BLOCK];
        float4 f2 = row4[i + 2 * BLOCK];
        float4 f3 = row4[i + 3 * BLOCK];
        float4 f4 = row4[i + 4 * BLOCK];
        float4 f5 = row4[i + 5 * BLOCK];
        float4 f6 = row4[i + 6 * BLOCK];
        float4 f7 = row4[i + 7 * BLOCK];
        m[0] = fmaxf(m[0], hmax4(f0));
        m[1] = fmaxf(m[1], hmax4(f1));
        m[2] = fmaxf(m[2], hmax4(f2));
        m[3] = fmaxf(m[3], hmax4(f3));
        m[4] = fmaxf(m[4], hmax4(f4));
        m[5] = fmaxf(m[5], hmax4(f5));
        m[6] = fmaxf(m[6], hmax4(f6));
        m[7] = fmaxf(m[7], hmax4(f7));
    }
    for (; i < V4; i += BLOCK) {                  // tail: up to 6 float4
        float4 f = row4[i];
        m[0] = fmaxf(m[0], hmax4(f));
    }
    const float tm = fmaxf(fmaxf(fmaxf(m[0], m[1]), fmaxf(m[2], m[3])),
                           fmaxf(fmaxf(m[4], m[5]), fmaxf(m[6], m[7])));
    smax[tid] = tm;
    __syncthreads();

    // ---------------- tau = 8th-largest of 256 stream maxes -----------------
    // tau <= true g8: top-8 values occupy <=8 streams, so the 8th-largest
    // stream max cannot exceed the 8th-largest value.
    if (wave == 0) {
        float L[TOPK];
        #pragma unroll
        for (int j = 0; j < TOPK; ++j) L[j] = -INFINITY;
        net8(L, smax[lane]);
        net8(L, smax[lane + 64]);
        net8(L, smax[lane + 128]);
        net8(L, smax[lane + 192]);
        wave_extract8(L, lane, sm8);
        if (lane == 0) s_g8 = sm8[TOPK - 1];
    }
    __syncthreads();
    const float g8 = s_g8;

    // ---------------- hot threads: stream may contain a candidate ----------
    if (tm >= g8) {
        int p = atomicAdd(&s_nhot, 1);
        if (p < HOTCAP) s_hot[p] = tid;
    }
    __syncthreads();

    // The 2 floats outside the aligned float4 body, checked directly.
    if (tid == 0) {
        #pragma unroll
        for (int e = 0; e < 2; ++e) {
            const int idx = ofs ? e : (V4 * 4 + e);
            const float f = rowf[idx];
            if (f >= g8) {
                int p = atomicAdd(&s_ncand, 1);
                if (p < CAP) sh_cand64[p] = fkey(f, (unsigned)idx);
            }
        }
    }

    // ---------------- sparse rescan of hot streams --------------------------
    if (s_nhot <= HOTCAP) {
        const int nhot = s_nhot;
        const int total = nhot * NK4;
        for (int w = tid; w < total; w += BLOCK) {
            const int h = w / NK4;                // const-div -> magic mul
            const int k = w - h * NK4;
            const int i4 = s_hot[h] + (k << 8);   // stride BLOCK in float4 space
            if (i4 < V4) {
                const float4 f = row4[i4];
                const int base = ofs + 4 * i4;
                if (f.x >= g8) { int p = atomicAdd(&s_ncand, 1); if (p < CAP) sh_cand64[p] = fkey(f.x, (unsigned)base); }
                if (f.y >= g8) { int p = atomicAdd(&s_ncand, 1); if (p < CAP) sh_cand64[p] = fkey(f.y, (unsigned)(base + 1)); }
                if (f.z >= g8) { int p = atomicAdd(&s_ncand, 1); if (p < CAP) sh_cand64[p] = fkey(f.z, (unsigned)(base + 2)); }
                if (f.w >= g8) { int p = atomicAdd(&s_ncand, 1); if (p < CAP) sh_cand64[p] = fkey(f.w, (unsigned)(base + 3)); }
            }
        }
    } else {                                      // massive-tie fallback: full rescan
        for (int i4 = tid; i4 < V4; i4 += BLOCK) {
            const float4 f = row4[i4];
            const int base = ofs + 4 * i4;
            if (f.x >= g8) { int p = atomicAdd(&s_ncand, 1); if (p < CAP) sh_cand64[p] = fkey(f.x, (unsigned)base); }
            if (f.y >= g8) { int p = atomicAdd(&s_ncand, 1); if (p < CAP) sh_cand64[p] = fkey(f.y, (unsigned)(base + 1)); }
            if (f.z >= g8) { int p = atomicAdd(&s_ncand, 1); if (p < CAP) sh_cand64[p] = fkey(f.z, (unsigned)(base + 2)); }
            if (f.w >= g8) { int p = atomicAdd(&s_ncand, 1); if (p < CAP) sh_cand64[p] = fkey(f.w, (unsigned)(base + 3)); }
        }
    }
    __syncthreads();
    const int ncand = min(s_ncand, CAP);          // >= 8 by construction

    // ---------------- exact top-8, wave 0 only, BARRIER-FREE ----------------
    // Only wave 0 touches sh_cand64 after the barrier above; wave64 lockstep
    // makes the per-iteration __syncthreads of the old version unnecessary.
    if (wave == 0) {
        for (int it = 0; it < TOPK; ++it) {
            unsigned long long mm = 0ull; int ms = 0;
            for (int j = lane; j < ncand; j += 64) {
                unsigned long long x = sh_cand64[j];
                if (x > mm) { mm = x; ms = j; }
            }
            #pragma unroll
            for (int off = 32; off; off >>= 1) {
                unsigned long long om = __shfl_down(mm, off, 64);
                int os = __shfl_down(ms, off, 64);
                if (om > mm) { mm = om; ms = os; }
            }
            if (lane == 0) {
                cand_out[pos * TOPK + it] =
                    (mm == 0ull) ? 0 : (int)(~(unsigned int)mm);
                sh_cand64[ms] = 0ull;             // pop for next round
            }
        }
    }
}

// ======================= Kernel 2: score + argmax + blend ==================
// One wave per position, no LDS, no barriers. dg/se rows live in registers;
// all 24 candidate-embedding float4 loads are issued up-front for full MLP.
__global__ __launch_bounds__(64) void dvat_score(
    const float* __restrict__ delta_grad,   // [B,S,D]
    const float* __restrict__ src_embeds,   // [B,S,D]
    const float* __restrict__ emb,          // [V,D]
    const int*   __restrict__ src_tokens,   // [B,S]
    const int*   __restrict__ attn,         // [B,S]
    const float* __restrict__ rand_u,       // [B,S]
    const int*   __restrict__ cand_in,      // [B*S, 8]
    int* __restrict__ out)                  // [B,S]
{
    const int pos = blockIdx.x;
    const int lane = threadIdx.x;           // 0..63

    // topk_idx *= attention_mask  (mask==0 -> all candidate indices 0)
    const bool amask = (attn[pos] != 0);
    int cand[TOPK];
    #pragma unroll
    for (int k = 0; k < TOPK; ++k)
        cand[k] = amask ? cand_in[pos * TOPK + k] : 0;

    // dg/se rows: 3 float4 per lane (D/4 = 192 = 3*64)
    const float4* dg4 = (const float4*)(delta_grad + (size_t)pos * D);
    const float4* se4 = (const float4*)(src_embeds + (size_t)pos * D);
    float4 g0 = dg4[lane], g1 = dg4[lane + 64], g2 = dg4[lane + 128];
    float4 e0 = se4[lane], e1 = se4[lane + 64], e2 = se4[lane + 128];

    // all candidate embedding fragments up-front (24 float4 in flight)
    float4 q[TOPK][3];
    #pragma unroll
    for (int k = 0; k < TOPK; ++k) {
        const float4* ev4 = (const float4*)(emb + (size_t)cand[k] * D);
        q[k][0] = ev4[lane];
        q[k][1] = ev4[lane + 64];
        q[k][2] = ev4[lane + 128];
    }

    // prev_dot / src_sq (fp64)
    double pd = 0.0, ssq = 0.0;
    {
        const float4 gs[3] = {g0, g1, g2};
        const float4 es[3] = {e0, e1, e2};
        #pragma unroll
        for (int t = 0; t < 3; ++t) {
            const float4 g = gs[t], e = es[t];
            pd  += (double)g.x * (double)e.x + (double)g.y * (double)e.y
                 + (double)g.z * (double)e.z + (double)g.w * (double)e.w;
            ssq += (double)e.x * (double)e.x + (double)e.y * (double)e.y
                 + (double)e.z * (double)e.z + (double)e.w * (double)e.w;
        }
    }
    #pragma unroll
    for (int off = 32; off; off >>= 1) {
        pd  += __shfl_down(pd, off, 64);
        ssq += __shfl_down(ssq, off, 64);
    }
    // lane 0 now holds prev_dot (pd) and src_sq (ssq)

    // ---------------- score 8 candidates + online filtered argmax -----------
    int best = 0; double best_s = 0.0; bool found = false;
    const int src_tok = src_tokens[pos];

    #pragma unroll
    for (int k = 0; k < TOPK; ++k) {
        const float4 gs[3] = {g0, g1, g2};
        const float4 es[3] = {e0, e1, e2};
        double ddg = 0.0, dse = 0.0, dvv = 0.0;
        #pragma unroll
        for (int t = 0; t < 3; ++t) {
            const float4 e = q[k][t];
            const float4 g = gs[t], s = es[t];
            ddg += (double)e.x * (double)g.x + (double)e.y * (double)g.y
                 + (double)e.z * (double)g.z + (double)e.w * (double)g.w;
            dse += (double)e.x * (double)s.x + (double)e.y * (double)s.y
                 + (double)e.z * (double)s.z + (double)e.w * (double)s.w;
            dvv += (double)e.x * (double)e.x + (double)e.y * (double)e.y
                 + (double)e.z * (double)e.z + (double)e.w * (double)e.w;
        }
        #pragma unroll
        for (int off = 32; off; off >>= 1) {
            ddg += __shfl_down(ddg, off, 64);
            dse += __shfl_down(dse, off, 64);
            dvv += __shfl_down(dvv, off, 64);
        }
        if (lane == 0) {
            const int v = cand[k];
            if (v >= NUM_SPECIAL && v != src_tok) {      // else -inf in reference
                double sq = ssq + dvv - 2.0 * dse;
                if (sq < 0.0) sq = 0.0;
                const double dn = sqrt(sq + 1e-20);
                const double sc = (ddg - pd) / dn;       // dir_dot_grad / dir_norm
                // jnp.argmax: lowest index wins ties
                if (!found || sc > best_s || (sc == best_s && v < best)) {
                    best = v; best_s = sc; found = true;
                }
            }
        }
    }

    if (lane == 0) {
        const int adv_flip = found ? best : 0;   // argmax of all -inf -> 0
        const bool no_special = (src_tok >= NUM_SPECIAL);
        const bool swap = (rand_u[pos] > 0.7f);  // 1.0 - SWAP_RATIO in f32
        out[pos] = (no_special && swap) ? adv_flip : src_tok;
    }
}

extern "C" void kernel_launch(void* const* d_in, const int* in_sizes, int n_in,
                              void* d_out, int out_size, void* d_ws, size_t ws_size,
                              hipStream_t stream) {
    const float* delta_grad = (const float*)d_in[0];
    const float* src_embeds = (const float*)d_in[1];
    const float* emb        = (const float*)d_in[2];
    const int*   src_tokens = (const int*)d_in[3];
    const float* pred_lm    = (const float*)d_in[4];
    const int*   attn       = (const int*)d_in[5];
    const float* randu      = (const float*)d_in[6];
    int* out = (int*)d_out;

    const int BS = in_sizes[3];   // B*S = 2048 positions
    int* cand_ws = (int*)d_ws;    // 2048*8 ints = 64 KB of workspace

    dvat_topk<<<BS, BLOCK, 0, stream>>>(pred_lm, cand_ws);
    dvat_score<<<BS, 64, 0, stream>>>(delta_grad, src_embeds, emb,
                                      src_tokens, attn, randu, cand_ws, out);
}